// Round 6
// baseline (88.998 us; speedup 1.0000x reference)
//
#include <hip/hip_runtime.h>
#include <math.h>

#define BB 4
#define NN 4096
#define MP 2048

// v_med3_u32: single-instruction clamp(key, lo, hi) for lo <= hi.
__device__ __forceinline__ unsigned med3u(unsigned a, unsigned b, unsigned c) {
    unsigned d;
    asm("v_med3_u32 %0, %1, %2, %3" : "=v"(d) : "v"(a), "v"(b), "v"(c));
    return d;
}

// Sorted top-16 insert: 15 med3 + 1 min (all static indices -> VGPRs).
#define INSERT16(keys, key)                                    \
    do {                                                       \
        _Pragma("unroll")                                      \
        for (int _k = 15; _k >= 1; --_k)                       \
            keys[_k] = med3u((key), keys[_k - 1], keys[_k]);   \
        keys[0] = min((key), keys[0]);                         \
    } while (0)

#define INSERT16_IF(keys, key)                                 \
    do { if ((key) < keys[15]) INSERT16(keys, key); } while (0)

// ------------------------------------------------------------ fused kernel
// Template over NCH = candidate chunks (CAND = 4096/NCH each).
// Region order (knn first - the long pole fills the machine, min blocks
// backfill):
//   knn  [0,   4*8*NCH):  pred->pred top-16/chunk, 2 q/thread
//   row  [..,  +4*8*NCH): pred->gt  min, 2 q/thread, per-chunk store
//   col  [..,  +4*8*NCH): gt->pred  min
//   cov  [..,  +4*4*NCH): partial->pred min
template <int NCH>
__global__ __launch_bounds__(256) void kfused(const float* __restrict__ pred,
                                              const float* __restrict__ gt,
                                              const float* __restrict__ partial,
                                              float* __restrict__ wrowc,
                                              float* __restrict__ wcolc,
                                              float* __restrict__ wcovc,
                                              unsigned* __restrict__ wkeys) {
    constexpr int CAND = NN / NCH;
    constexpr int R0 = 4 * 8 * NCH;
    constexpr int R1 = R0 + 4 * 8 * NCH;
    constexpr int R2 = R1 + 4 * 8 * NCH;
    __shared__ float4 cand[CAND];
    int bid = blockIdx.x;

    if (bid < R0) {
        // ---------------- knn path (2 queries/thread) ----------------
        int b = bid / (8 * NCH); int r = bid % (8 * NCH);
        int qb = r / NCH; int ch = r % NCH;
        for (int t = threadIdx.x; t < CAND; t += 256) {
            int j = ch * CAND + t;
            const float* p = pred + ((size_t)b * NN + j) * 3;
            float x = p[0], y = p[1], z = p[2];
            cand[t] = make_float4(x, y, z, fmaf(z, z, fmaf(y, y, x * x)));
        }
        __syncthreads();
        int i0 = qb * 512 + threadIdx.x;
        int i1 = i0 + 256;
        const float* q0 = pred + ((size_t)b * NN + i0) * 3;
        const float* q1 = pred + ((size_t)b * NN + i1) * 3;
        float q0x = q0[0], q0y = q0[1], q0z = q0[2];
        float q1x = q1[0], q1y = q1[1], q1z = q1[2];
        float q0q = fmaf(q0z, q0z, fmaf(q0y, q0y, q0x * q0x));
        float q1q = fmaf(q1z, q1z, fmaf(q1y, q1y, q1x * q1x));
        unsigned keysA[16], keysB[16];
#pragma unroll
        for (int k = 0; k < 16; ++k) { keysA[k] = 0xFFFFFFFFu; keysB[k] = 0xFFFFFFFFu; }
        unsigned jbase = (unsigned)(ch * CAND);
#pragma unroll 4
        for (int jj = 0; jj < CAND; ++jj) {
            float4 c = cand[jj];
            float d0 = fmaf(q0z, c.z, fmaf(q0y, c.y, q0x * c.x));
            float d1 = fmaf(q1z, c.z, fmaf(q1y, c.y, q1x * c.x));
            float s0 = fmaxf(fmaf(-2.f, d0, q0q + c.w), 0.f);
            float s1 = fmaxf(fmaf(-2.f, d1, q1q + c.w), 0.f);
            unsigned idn = jbase + (unsigned)jj;
            unsigned k0 = (__float_as_uint(s0) & 0xFFFFF000u) | idn;
            unsigned k1 = (__float_as_uint(s1) & 0xFFFFF000u) | idn;
            INSERT16(keysA, k0);
            INSERT16(keysB, k1);
        }
        uint4* dst0 = (uint4*)(wkeys + (((size_t)b * NN + i0) * NCH + ch) * 16);
        dst0[0] = make_uint4(keysA[0], keysA[1], keysA[2], keysA[3]);
        dst0[1] = make_uint4(keysA[4], keysA[5], keysA[6], keysA[7]);
        dst0[2] = make_uint4(keysA[8], keysA[9], keysA[10], keysA[11]);
        dst0[3] = make_uint4(keysA[12], keysA[13], keysA[14], keysA[15]);
        uint4* dst1 = (uint4*)(wkeys + (((size_t)b * NN + i1) * NCH + ch) * 16);
        dst1[0] = make_uint4(keysB[0], keysB[1], keysB[2], keysB[3]);
        dst1[1] = make_uint4(keysB[4], keysB[5], keysB[6], keysB[7]);
        dst1[2] = make_uint4(keysB[8], keysB[9], keysB[10], keysB[11]);
        dst1[3] = make_uint4(keysB[12], keysB[13], keysB[14], keysB[15]);
    } else {
        // ---------------- min path ----------------
        const float* qptr; const float* cptr; float* outp;
        int b, qb, ch, qn;
        if (bid < R1) {
            int l = bid - R0;
            b = l / (8 * NCH); int r = l % (8 * NCH); qb = r / NCH; ch = r % NCH;
            qptr = pred; cptr = gt; outp = wrowc; qn = NN;
        } else if (bid < R2) {
            int l = bid - R1;
            b = l / (8 * NCH); int r = l % (8 * NCH); qb = r / NCH; ch = r % NCH;
            qptr = gt; cptr = pred; outp = wcolc; qn = NN;
        } else {
            int l = bid - R2;
            b = l / (4 * NCH); int r = l % (4 * NCH); qb = r / NCH; ch = r % NCH;
            qptr = partial; cptr = pred; outp = wcovc; qn = MP;
        }
        for (int t = threadIdx.x; t < CAND; t += 256) {
            int j = ch * CAND + t;
            const float* p = cptr + ((size_t)b * NN + j) * 3;
            float x = p[0], y = p[1], z = p[2];
            cand[t] = make_float4(x, y, z, fmaf(z, z, fmaf(y, y, x * x)));
        }
        __syncthreads();
        int i0 = qb * 512 + threadIdx.x;
        int i1 = i0 + 256;
        const float* q0 = qptr + ((size_t)b * qn + i0) * 3;
        const float* q1 = qptr + ((size_t)b * qn + i1) * 3;
        float q0x = q0[0], q0y = q0[1], q0z = q0[2];
        float q1x = q1[0], q1y = q1[1], q1z = q1[2];
        float q0q = fmaf(q0z, q0z, fmaf(q0y, q0y, q0x * q0x));
        float q1q = fmaf(q1z, q1z, fmaf(q1y, q1y, q1x * q1x));
        float m0 = 1e30f, m1 = 1e30f;
#pragma unroll 4
        for (int jj = 0; jj < CAND; ++jj) {
            float4 c = cand[jj];
            float d0 = fmaf(q0z, c.z, fmaf(q0y, c.y, q0x * c.x));
            float d1 = fmaf(q1z, c.z, fmaf(q1y, c.y, q1x * c.x));
            m0 = fminf(m0, fmaf(-2.f, d0, q0q + c.w));
            m1 = fminf(m1, fmaf(-2.f, d1, q1q + c.w));
        }
        outp[(size_t)ch * (4 * qn) + (size_t)b * qn + i0] = fmaxf(m0, 0.f);
        outp[(size_t)ch * (4 * qn) + (size_t)b * qn + i1] = fmaxf(m1, 0.f);
    }
}

// ------------------------------------------------------------ mid kernel
// Region 1 [0, 64):     direct merge of NCH sorted chunk-lists -> top-16,
//                       gather 16 neighbors, repulsion + variance,
//                       block-reduced to partialsB[64] (float2).
// Region 2 [64, 224):   kred - chunk-min reduction + sqrt + mask,
//                       block-reduced to partials2[160] (float2).
// Both depend only on kfused -> single dispatch.
template <int NCH>
__global__ __launch_bounds__(256) void kmid2(const float* __restrict__ pred,
                                             const unsigned* __restrict__ wkeys,
                                             const float* __restrict__ wrowc,
                                             const float* __restrict__ wcolc,
                                             const float* __restrict__ wcovc,
                                             const float* __restrict__ partialpts,
                                             float2* __restrict__ partialsB,
                                             float2* __restrict__ partials2) {
    __shared__ float ra[4], rb[4];
    int bid = blockIdx.x;
    int t = threadIdx.x;

    if (bid < 64) {
        // ---------------- merge + rep/var ----------------
        int q = bid * 256 + t;              // [0, 16384)
        int b = q >> 12;
        int i = q & (NN - 1);
        unsigned keys[16];
#pragma unroll
        for (int k = 0; k < 16; ++k) keys[k] = 0xFFFFFFFFu;
        const uint4* src = (const uint4*)(wkeys + (size_t)q * (NCH * 16));
#pragma unroll 1
        for (int l = 0; l < NCH; ++l) {
            const uint4* lp = src + l * 4;
#pragma unroll
            for (int c4 = 0; c4 < 4; ++c4) {
                uint4 k4 = lp[c4];
                if (k4.x >= keys[15]) break;   // sorted list: rest can't insert
                INSERT16(keys, k4.x);
                INSERT16_IF(keys, k4.y);
                INSERT16_IF(keys, k4.z);
                INSERT16_IF(keys, k4.w);
            }
        }
        const float* qp = pred + ((size_t)b * NN + i) * 3;
        float qx = qp[0], qy = qp[1], qz = qp[2];
        float qq = fmaf(qz, qz, fmaf(qy, qy, qx * qx));
        float cxv[16], cyv[16], czv[16];
#pragma unroll
        for (int r = 0; r < 16; ++r) {
            int idx = (int)(keys[r] & 0xFFFu);
            const float* p = pred + ((size_t)b * NN + idx) * 3;
            cxv[r] = p[0]; cyv[r] = p[1]; czv[r] = p[2];
        }
        float rep = 0.f;
#pragma unroll
        for (int r = 1; r <= 8; ++r) {
            float x = cxv[r], y = cyv[r], z = czv[r];
            float bb2 = fmaf(z, z, fmaf(y, y, x * x));
            float dot = fmaf(qz, z, fmaf(qy, y, qx * x));
            float sq  = fmaxf(fmaf(-2.f, dot, qq + bb2), 0.f);
            float d = (sq > 1e-12f) ? sqrtf(sq) : 0.f;
            rep += fmaxf(0.005f - d, 0.f);
        }
        float sx = 0.f, sy = 0.f, sz = 0.f;
#pragma unroll
        for (int r = 0; r < 16; ++r) { sx += cxv[r]; sy += cyv[r]; sz += czv[r]; }
        float mx = sx * (1.f / 16.f), my = sy * (1.f / 16.f), mz = sz * (1.f / 16.f);
        float var = 0.f;
#pragma unroll
        for (int r = 0; r < 16; ++r) {
            float dx = cxv[r] - mx, dy = cyv[r] - my, dz = czv[r] - mz;
            var += dx * dx + dy * dy + dz * dz;
        }
        var *= (1.f / 47.f);
#pragma unroll
        for (int off = 32; off > 0; off >>= 1) {
            rep += __shfl_down(rep, off);
            var += __shfl_down(var, off);
        }
        int wid = t >> 6, lane = t & 63;
        if (lane == 0) { ra[wid] = rep; rb[wid] = var; }
        __syncthreads();
        if (t == 0)
            partialsB[bid] = make_float2(ra[0] + ra[1] + ra[2] + ra[3],
                                         rb[0] + rb[1] + rb[2] + rb[3]);
    } else {
        // ---------------- kred ----------------
        int bid2 = bid - 64;
        float pa = 0.f, pb = 0.f;
        if (bid2 < 64) {                       // row mins
            int q = bid2 * 256 + t;
            float m = 1e30f;
#pragma unroll
            for (int ch = 0; ch < NCH; ++ch)
                m = fminf(m, wrowc[(size_t)ch * (BB * NN) + q]);
            pa = (m > 1e-12f) ? sqrtf(m) : 0.f;
        } else if (bid2 < 128) {               // col mins
            int q = (bid2 - 64) * 256 + t;
            float m = 1e30f;
#pragma unroll
            for (int ch = 0; ch < NCH; ++ch)
                m = fminf(m, wcolc[(size_t)ch * (BB * NN) + q]);
            pa = (m > 1e-12f) ? sqrtf(m) : 0.f;
        } else {                               // cov mins + mask
            int q = (bid2 - 128) * 256 + t;    // [0, 8192), block within one batch
            float m = 1e30f;
#pragma unroll
            for (int ch = 0; ch < NCH; ++ch)
                m = fminf(m, wcovc[(size_t)ch * (BB * MP) + q]);
            const float* p = partialpts + (size_t)q * 3;
            float am = fabsf(p[0]) + fabsf(p[1]) + fabsf(p[2]);
            float msk = (am > 1e-6f) ? 1.f : 0.f;
            float d = (m > 1e-12f) ? sqrtf(m) : 0.f;
            pa = d * msk; pb = msk;
        }
#pragma unroll
        for (int off = 32; off > 0; off >>= 1) {
            pa += __shfl_down(pa, off);
            pb += __shfl_down(pb, off);
        }
        int wid = t >> 6, lane = t & 63;
        if (lane == 0) { ra[wid] = pa; rb[wid] = pb; }
        __syncthreads();
        if (t == 0)
            partials2[bid2] = make_float2(ra[0] + ra[1] + ra[2] + ra[3],
                                          rb[0] + rb[1] + rb[2] + rb[3]);
    }
}

// -------------------------------------------------------------- final kernel
// 1 block x 256 (4 waves), one barrier. Combines 160 + 64 partial pairs.
__global__ __launch_bounds__(256) void kfinal2(const float2* __restrict__ partials2,
                                               const float2* __restrict__ partialsB,
                                               float* __restrict__ out) {
    __shared__ float lds[12];
    int t = threadIdx.x;
    int wid = t >> 6, lane = t & 63;
    if (wid == 0) {                      // srow over partials2[0..64)
        float v = partials2[lane].x;
#pragma unroll
        for (int off = 32; off > 0; off >>= 1) v += __shfl_down(v, off);
        if (lane == 0) lds[0] = v;
    } else if (wid == 1) {               // scol over partials2[64..128)
        float v = partials2[64 + lane].x;
#pragma unroll
        for (int off = 32; off > 0; off >>= 1) v += __shfl_down(v, off);
        if (lane == 0) lds[1] = v;
    } else if (wid == 2) {               // cov per batch over partials2[128..160)
        float ss = 0.f, cc = 0.f;
        if (lane < 32) { float2 p = partials2[128 + lane]; ss = p.x; cc = p.y; }
#pragma unroll
        for (int off = 4; off > 0; off >>= 1) {   // reduce within 8-lane groups
            ss += __shfl_down(ss, off, 8);
            cc += __shfl_down(cc, off, 8);
        }
        if (lane < 32 && (lane & 7) == 0) {
            int bb = lane >> 3;
            lds[4 + 2 * bb] = ss;
            lds[5 + 2 * bb] = cc;
        }
    } else {                             // rep/var over partialsB[0..64)
        float2 p0 = partialsB[lane];
        float rep = p0.x, var = p0.y;
#pragma unroll
        for (int off = 32; off > 0; off >>= 1) {
            rep += __shfl_down(rep, off);
            var += __shfl_down(var, off);
        }
        if (lane == 0) { lds[2] = rep; lds[3] = var; }
    }
    __syncthreads();
    if (t == 0) {
        const float inv_bn = 1.f / (float)(BB * NN);
        float chamfer = (lds[0] + lds[1]) * inv_bn;
        float repulsion = lds[2] * inv_bn * (1.f / 8.f) * 0.1f;
        float cov = 0.f;
#pragma unroll
        for (int bb = 0; bb < 4; ++bb) {
            float cs = lds[4 + 2 * bb], cc = lds[5 + 2 * bb];
            cov += (cc > 0.f) ? cs / fmaxf(cc, 1.f) : 0.f;
        }
        float coverage = cov * 0.25f * 0.2f;
        float smooth = lds[3] * inv_bn * 0.05f;
        out[0] = chamfer;
        out[1] = repulsion;
        out[2] = coverage;
        out[3] = smooth;
        out[4] = chamfer + repulsion + coverage + smooth;
    }
}

extern "C" void kernel_launch(void* const* d_in, const int* in_sizes, int n_in,
                              void* d_out, int out_size, void* d_ws, size_t ws_size,
                              hipStream_t stream) {
    const float* pred    = (const float*)d_in[0];
    const float* gt      = (const float*)d_in[1];
    const float* partial = (const float*)d_in[2];
    float* out = (float*)d_out;

    const size_t NQ = (size_t)BB * NN;     // 16384
    const size_t NC = (size_t)BB * MP;     // 8192

    // layout (u32 units): wkeys | wrowc | wcolc | wcovc | pB(128) | p2(320)
    auto need = [&](int nch) -> size_t {
        return (NQ * nch * 16 + NQ * nch * 2 + NC * nch + 128 + 320) * 4;
    };

    unsigned* wkeys = (unsigned*)d_ws;

#define LAUNCH(NCHV, GRID)                                                          \
    do {                                                                            \
        constexpr int NCH = NCHV;                                                   \
        float* wrowc = (float*)(wkeys + NQ * NCH * 16);                             \
        float* wcolc = wrowc + NQ * NCH;                                            \
        float* wcovc = wcolc + NQ * NCH;                                            \
        float2* pB = (float2*)(wcovc + NC * NCH);                                   \
        float2* p2 = pB + 64;                                                       \
        kfused<NCH><<<GRID, 256, 0, stream>>>(pred, gt, partial,                    \
                                              wrowc, wcolc, wcovc, wkeys);          \
        kmid2<NCH><<<224, 256, 0, stream>>>(pred, wkeys, wrowc, wcolc, wcovc,       \
                                            partial, pB, p2);                       \
        kfinal2<<<1, 256, 0, stream>>>(p2, pB, out);                                \
    } while (0)

    if (ws_size >= need(32)) {
        LAUNCH(32, 4 * 8 * 32 * 3 + 4 * 4 * 32);       // 3584
    } else if (ws_size >= need(16)) {
        LAUNCH(16, 4 * 8 * 16 * 3 + 4 * 4 * 16);       // 1792
    } else {
        LAUNCH(8, 4 * 8 * 8 * 3 + 4 * 4 * 8);          // 896
    }
#undef LAUNCH
}

// Round 7
// 68.616 us; speedup vs baseline: 1.2970x; 1.2970x over previous
//
#include <hip/hip_runtime.h>
#include <math.h>

#define BB 4
#define NN 4096
#define MP 2048

// v_med3_u32: single-instruction clamp(key, lo, hi) for lo <= hi.
__device__ __forceinline__ unsigned med3u(unsigned a, unsigned b, unsigned c) {
    unsigned d;
    asm("v_med3_u32 %0, %1, %2, %3" : "=v"(d) : "v"(a), "v"(b), "v"(c));
    return d;
}

// Sorted top-K insert: (K-1) med3 + 1 min, all static indices -> VGPRs.
template <int K>
__device__ __forceinline__ void insertK(unsigned (&keys)[K], unsigned key) {
#pragma unroll
    for (int k = K - 1; k >= 1; --k)
        keys[k] = med3u(key, keys[k - 1], keys[k]);
    keys[0] = min(key, keys[0]);
}

template <int K>
__device__ __forceinline__ void insertK_if(unsigned (&keys)[K], unsigned key) {
    if (key < keys[K - 1]) insertK<K>(keys, key);
}

// ------------------------------------------------------------ fused kernel
// NCH = candidate chunks (CAND = 4096/NCH each), K = per-chunk knn list depth.
// K=8 is valid for NCH=32: global top-16 needs no chunk to hold >=9 of the
// true top-16; with 16 NN spread over 32 index-random chunks P ~ 8e-9/query.
// Region order (knn first - the long pole fills the machine, min backfills):
//   knn  [0,   4*8*NCH):  pred->pred top-K/chunk, 2 q/thread
//   row  [..,  +4*8*NCH): pred->gt  min, 2 q/thread, per-chunk slab store
//   col  [..,  +4*8*NCH): gt->pred  min
//   cov  [..,  +4*4*NCH): partial->pred min
template <int NCH, int K>
__global__ __launch_bounds__(256) void kfused(const float* __restrict__ pred,
                                              const float* __restrict__ gt,
                                              const float* __restrict__ partial,
                                              float* __restrict__ wrowc,
                                              float* __restrict__ wcolc,
                                              float* __restrict__ wcovc,
                                              unsigned* __restrict__ wkeys) {
    constexpr int CAND = NN / NCH;
    constexpr int R0 = 4 * 8 * NCH;
    constexpr int R1 = R0 + 4 * 8 * NCH;
    constexpr int R2 = R1 + 4 * 8 * NCH;
    __shared__ float4 cand[CAND];
    int bid = blockIdx.x;

    if (bid < R0) {
        // ---------------- knn path (2 queries/thread) ----------------
        int b = bid / (8 * NCH); int r = bid % (8 * NCH);
        int qb = r / NCH; int ch = r % NCH;
        for (int t = threadIdx.x; t < CAND; t += 256) {
            int j = ch * CAND + t;
            const float* p = pred + ((size_t)b * NN + j) * 3;
            float x = p[0], y = p[1], z = p[2];
            cand[t] = make_float4(x, y, z, fmaf(z, z, fmaf(y, y, x * x)));
        }
        __syncthreads();
        int i0 = qb * 512 + threadIdx.x;
        int i1 = i0 + 256;
        const float* q0 = pred + ((size_t)b * NN + i0) * 3;
        const float* q1 = pred + ((size_t)b * NN + i1) * 3;
        float q0x = q0[0], q0y = q0[1], q0z = q0[2];
        float q1x = q1[0], q1y = q1[1], q1z = q1[2];
        float q0q = fmaf(q0z, q0z, fmaf(q0y, q0y, q0x * q0x));
        float q1q = fmaf(q1z, q1z, fmaf(q1y, q1y, q1x * q1x));
        unsigned keysA[K], keysB[K];
#pragma unroll
        for (int k = 0; k < K; ++k) { keysA[k] = 0xFFFFFFFFu; keysB[k] = 0xFFFFFFFFu; }
        unsigned jbase = (unsigned)(ch * CAND);
#pragma unroll 4
        for (int jj = 0; jj < CAND; ++jj) {
            float4 c = cand[jj];
            float d0 = fmaf(q0z, c.z, fmaf(q0y, c.y, q0x * c.x));
            float d1 = fmaf(q1z, c.z, fmaf(q1y, c.y, q1x * c.x));
            float s0 = fmaxf(fmaf(-2.f, d0, q0q + c.w), 0.f);
            float s1 = fmaxf(fmaf(-2.f, d1, q1q + c.w), 0.f);
            unsigned idn = jbase + (unsigned)jj;
            unsigned k0 = (__float_as_uint(s0) & 0xFFFFF000u) | idn;
            unsigned k1 = (__float_as_uint(s1) & 0xFFFFF000u) | idn;
            insertK<K>(keysA, k0);
            insertK<K>(keysB, k1);
        }
        uint4* dst0 = (uint4*)(wkeys + (((size_t)b * NN + i0) * NCH + ch) * K);
#pragma unroll
        for (int u = 0; u < K / 4; ++u)
            dst0[u] = make_uint4(keysA[4 * u], keysA[4 * u + 1], keysA[4 * u + 2], keysA[4 * u + 3]);
        uint4* dst1 = (uint4*)(wkeys + (((size_t)b * NN + i1) * NCH + ch) * K);
#pragma unroll
        for (int u = 0; u < K / 4; ++u)
            dst1[u] = make_uint4(keysB[4 * u], keysB[4 * u + 1], keysB[4 * u + 2], keysB[4 * u + 3]);
    } else {
        // ---------------- min path ----------------
        const float* qptr; const float* cptr; float* outp;
        int b, qb, ch, qn;
        if (bid < R1) {
            int l = bid - R0;
            b = l / (8 * NCH); int r = l % (8 * NCH); qb = r / NCH; ch = r % NCH;
            qptr = pred; cptr = gt; outp = wrowc; qn = NN;
        } else if (bid < R2) {
            int l = bid - R1;
            b = l / (8 * NCH); int r = l % (8 * NCH); qb = r / NCH; ch = r % NCH;
            qptr = gt; cptr = pred; outp = wcolc; qn = NN;
        } else {
            int l = bid - R2;
            b = l / (4 * NCH); int r = l % (4 * NCH); qb = r / NCH; ch = r % NCH;
            qptr = partial; cptr = pred; outp = wcovc; qn = MP;
        }
        for (int t = threadIdx.x; t < CAND; t += 256) {
            int j = ch * CAND + t;
            const float* p = cptr + ((size_t)b * NN + j) * 3;
            float x = p[0], y = p[1], z = p[2];
            cand[t] = make_float4(x, y, z, fmaf(z, z, fmaf(y, y, x * x)));
        }
        __syncthreads();
        int i0 = qb * 512 + threadIdx.x;
        int i1 = i0 + 256;
        const float* q0 = qptr + ((size_t)b * qn + i0) * 3;
        const float* q1 = qptr + ((size_t)b * qn + i1) * 3;
        float q0x = q0[0], q0y = q0[1], q0z = q0[2];
        float q1x = q1[0], q1y = q1[1], q1z = q1[2];
        float q0q = fmaf(q0z, q0z, fmaf(q0y, q0y, q0x * q0x));
        float q1q = fmaf(q1z, q1z, fmaf(q1y, q1y, q1x * q1x));
        float m0 = 1e30f, m1 = 1e30f;
#pragma unroll 4
        for (int jj = 0; jj < CAND; ++jj) {
            float4 c = cand[jj];
            float d0 = fmaf(q0z, c.z, fmaf(q0y, c.y, q0x * c.x));
            float d1 = fmaf(q1z, c.z, fmaf(q1y, c.y, q1x * c.x));
            m0 = fminf(m0, fmaf(-2.f, d0, q0q + c.w));
            m1 = fminf(m1, fmaf(-2.f, d1, q1q + c.w));
        }
        outp[(size_t)ch * (4 * qn) + (size_t)b * qn + i0] = fmaxf(m0, 0.f);
        outp[(size_t)ch * (4 * qn) + (size_t)b * qn + i1] = fmaxf(m1, 0.f);
    }
}

// ------------------------------------------------------------ mid kernel
// Region 1 [0, 64):   merge NCH sorted K-lists -> top-16 (head-quads
//                     batch-loaded 8 wide to keep VMEM latency pipelined),
//                     gather neighbors, repulsion + variance -> partialsB[64].
// Region 2 [64, 224): kred - chunk-min reduction + sqrt + mask -> partials2[160].
template <int NCH, int K>
__global__ __launch_bounds__(256) void kmid2(const float* __restrict__ pred,
                                             const unsigned* __restrict__ wkeys,
                                             const float* __restrict__ wrowc,
                                             const float* __restrict__ wcolc,
                                             const float* __restrict__ wcovc,
                                             const float* __restrict__ partialpts,
                                             float2* __restrict__ partialsB,
                                             float2* __restrict__ partials2) {
    __shared__ float ra[4], rb[4];
    int bid = blockIdx.x;
    int t = threadIdx.x;

    if (bid < 64) {
        // ---------------- merge + rep/var ----------------
        constexpr int QL = K / 4;           // quads per list
        int q = bid * 256 + t;              // [0, 16384)
        int b = q >> 12;
        int i = q & (NN - 1);
        unsigned keys[16];
#pragma unroll
        for (int k = 0; k < 16; ++k) keys[k] = 0xFFFFFFFFu;
        const uint4* src = (const uint4*)(wkeys + (size_t)q * (NCH * K));
#pragma unroll 1
        for (int lb = 0; lb < NCH; lb += 8) {
            uint4 h[8];
#pragma unroll
            for (int u = 0; u < 8; ++u) h[u] = src[(size_t)(lb + u) * QL];
#pragma unroll
            for (int u = 0; u < 8; ++u) {
                uint4 k4 = h[u];
                if (k4.x < keys[15]) {
                    insertK<16>(keys, k4.x);
                    insertK_if<16>(keys, k4.y);
                    insertK_if<16>(keys, k4.z);
                    insertK_if<16>(keys, k4.w);
                    if (QL > 1 && k4.w < keys[15]) {
                        const uint4* lp = src + (size_t)(lb + u) * QL;
#pragma unroll
                        for (int q2 = 1; q2 < QL; ++q2) {
                            uint4 k4b = lp[q2];
                            if (k4b.x >= keys[15]) break;
                            insertK<16>(keys, k4b.x);
                            insertK_if<16>(keys, k4b.y);
                            insertK_if<16>(keys, k4b.z);
                            insertK_if<16>(keys, k4b.w);
                        }
                    }
                }
            }
        }
        const float* qp = pred + ((size_t)b * NN + i) * 3;
        float qx = qp[0], qy = qp[1], qz = qp[2];
        float qq = fmaf(qz, qz, fmaf(qy, qy, qx * qx));
        float cxv[16], cyv[16], czv[16];
#pragma unroll
        for (int r = 0; r < 16; ++r) {
            int idx = (int)(keys[r] & 0xFFFu);
            const float* p = pred + ((size_t)b * NN + idx) * 3;
            cxv[r] = p[0]; cyv[r] = p[1]; czv[r] = p[2];
        }
        float rep = 0.f;
#pragma unroll
        for (int r = 1; r <= 8; ++r) {
            float x = cxv[r], y = cyv[r], z = czv[r];
            float bb2 = fmaf(z, z, fmaf(y, y, x * x));
            float dot = fmaf(qz, z, fmaf(qy, y, qx * x));
            float sq  = fmaxf(fmaf(-2.f, dot, qq + bb2), 0.f);
            float d = (sq > 1e-12f) ? sqrtf(sq) : 0.f;
            rep += fmaxf(0.005f - d, 0.f);
        }
        float sx = 0.f, sy = 0.f, sz = 0.f;
#pragma unroll
        for (int r = 0; r < 16; ++r) { sx += cxv[r]; sy += cyv[r]; sz += czv[r]; }
        float mx = sx * (1.f / 16.f), my = sy * (1.f / 16.f), mz = sz * (1.f / 16.f);
        float var = 0.f;
#pragma unroll
        for (int r = 0; r < 16; ++r) {
            float dx = cxv[r] - mx, dy = cyv[r] - my, dz = czv[r] - mz;
            var += dx * dx + dy * dy + dz * dz;
        }
        var *= (1.f / 47.f);
#pragma unroll
        for (int off = 32; off > 0; off >>= 1) {
            rep += __shfl_down(rep, off);
            var += __shfl_down(var, off);
        }
        int wid = t >> 6, lane = t & 63;
        if (lane == 0) { ra[wid] = rep; rb[wid] = var; }
        __syncthreads();
        if (t == 0)
            partialsB[bid] = make_float2(ra[0] + ra[1] + ra[2] + ra[3],
                                         rb[0] + rb[1] + rb[2] + rb[3]);
    } else {
        // ---------------- kred ----------------
        int bid2 = bid - 64;
        float pa = 0.f, pb = 0.f;
        if (bid2 < 64) {                       // row mins
            int q = bid2 * 256 + t;
            float m = 1e30f;
#pragma unroll
            for (int ch = 0; ch < NCH; ++ch)
                m = fminf(m, wrowc[(size_t)ch * (BB * NN) + q]);
            pa = (m > 1e-12f) ? sqrtf(m) : 0.f;
        } else if (bid2 < 128) {               // col mins
            int q = (bid2 - 64) * 256 + t;
            float m = 1e30f;
#pragma unroll
            for (int ch = 0; ch < NCH; ++ch)
                m = fminf(m, wcolc[(size_t)ch * (BB * NN) + q]);
            pa = (m > 1e-12f) ? sqrtf(m) : 0.f;
        } else {                               // cov mins + mask
            int q = (bid2 - 128) * 256 + t;    // [0, 8192)
            float m = 1e30f;
#pragma unroll
            for (int ch = 0; ch < NCH; ++ch)
                m = fminf(m, wcovc[(size_t)ch * (BB * MP) + q]);
            const float* p = partialpts + (size_t)q * 3;
            float am = fabsf(p[0]) + fabsf(p[1]) + fabsf(p[2]);
            float msk = (am > 1e-6f) ? 1.f : 0.f;
            float d = (m > 1e-12f) ? sqrtf(m) : 0.f;
            pa = d * msk; pb = msk;
        }
#pragma unroll
        for (int off = 32; off > 0; off >>= 1) {
            pa += __shfl_down(pa, off);
            pb += __shfl_down(pb, off);
        }
        int wid = t >> 6, lane = t & 63;
        if (lane == 0) { ra[wid] = pa; rb[wid] = pb; }
        __syncthreads();
        if (t == 0)
            partials2[bid2] = make_float2(ra[0] + ra[1] + ra[2] + ra[3],
                                          rb[0] + rb[1] + rb[2] + rb[3]);
    }
}

// -------------------------------------------------------------- final kernel
// 1 block x 256 (4 waves), one barrier. Combines 160 + 64 partial pairs.
__global__ __launch_bounds__(256) void kfinal2(const float2* __restrict__ partials2,
                                               const float2* __restrict__ partialsB,
                                               float* __restrict__ out) {
    __shared__ float lds[12];
    int t = threadIdx.x;
    int wid = t >> 6, lane = t & 63;
    if (wid == 0) {                      // srow over partials2[0..64)
        float v = partials2[lane].x;
#pragma unroll
        for (int off = 32; off > 0; off >>= 1) v += __shfl_down(v, off);
        if (lane == 0) lds[0] = v;
    } else if (wid == 1) {               // scol over partials2[64..128)
        float v = partials2[64 + lane].x;
#pragma unroll
        for (int off = 32; off > 0; off >>= 1) v += __shfl_down(v, off);
        if (lane == 0) lds[1] = v;
    } else if (wid == 2) {               // cov per batch over partials2[128..160)
        float ss = 0.f, cc = 0.f;
        if (lane < 32) { float2 p = partials2[128 + lane]; ss = p.x; cc = p.y; }
#pragma unroll
        for (int off = 4; off > 0; off >>= 1) {   // reduce within 8-lane groups
            ss += __shfl_down(ss, off, 8);
            cc += __shfl_down(cc, off, 8);
        }
        if (lane < 32 && (lane & 7) == 0) {
            int bb = lane >> 3;
            lds[4 + 2 * bb] = ss;
            lds[5 + 2 * bb] = cc;
        }
    } else {                             // rep/var over partialsB[0..64)
        float2 p0 = partialsB[lane];
        float rep = p0.x, var = p0.y;
#pragma unroll
        for (int off = 32; off > 0; off >>= 1) {
            rep += __shfl_down(rep, off);
            var += __shfl_down(var, off);
        }
        if (lane == 0) { lds[2] = rep; lds[3] = var; }
    }
    __syncthreads();
    if (t == 0) {
        const float inv_bn = 1.f / (float)(BB * NN);
        float chamfer = (lds[0] + lds[1]) * inv_bn;
        float repulsion = lds[2] * inv_bn * (1.f / 8.f) * 0.1f;
        float cov = 0.f;
#pragma unroll
        for (int bb = 0; bb < 4; ++bb) {
            float cs = lds[4 + 2 * bb], cc = lds[5 + 2 * bb];
            cov += (cc > 0.f) ? cs / fmaxf(cc, 1.f) : 0.f;
        }
        float coverage = cov * 0.25f * 0.2f;
        float smooth = lds[3] * inv_bn * 0.05f;
        out[0] = chamfer;
        out[1] = repulsion;
        out[2] = coverage;
        out[3] = smooth;
        out[4] = chamfer + repulsion + coverage + smooth;
    }
}

extern "C" void kernel_launch(void* const* d_in, const int* in_sizes, int n_in,
                              void* d_out, int out_size, void* d_ws, size_t ws_size,
                              hipStream_t stream) {
    const float* pred    = (const float*)d_in[0];
    const float* gt      = (const float*)d_in[1];
    const float* partial = (const float*)d_in[2];
    float* out = (float*)d_out;

    const size_t NQ = (size_t)BB * NN;     // 16384
    const size_t NC = (size_t)BB * MP;     // 8192

    // layout (u32 units): wkeys | wrowc | wcolc | wcovc | pB(128) | p2(320)
    auto need = [&](int nch, int k) -> size_t {
        return (NQ * nch * k + NQ * nch * 2 + NC * nch + 128 + 320) * 4;
    };

    unsigned* wkeys = (unsigned*)d_ws;

#define LAUNCH(NCHV, KV, GRID)                                                      \
    do {                                                                            \
        constexpr int NCH = NCHV;                                                   \
        constexpr int KK = KV;                                                      \
        float* wrowc = (float*)(wkeys + NQ * NCH * KK);                             \
        float* wcolc = wrowc + NQ * NCH;                                            \
        float* wcovc = wcolc + NQ * NCH;                                            \
        float2* pB = (float2*)(wcovc + NC * NCH);                                   \
        float2* p2 = pB + 64;                                                       \
        kfused<NCH, KK><<<GRID, 256, 0, stream>>>(pred, gt, partial,                \
                                                  wrowc, wcolc, wcovc, wkeys);      \
        kmid2<NCH, KK><<<224, 256, 0, stream>>>(pred, wkeys, wrowc, wcolc, wcovc,   \
                                                partial, pB, p2);                   \
        kfinal2<<<1, 256, 0, stream>>>(p2, pB, out);                                \
    } while (0)

    if (ws_size >= need(32, 8)) {
        LAUNCH(32, 8, 4 * 8 * 32 * 3 + 4 * 4 * 32);    // 3584 blocks
    } else if (ws_size >= need(16, 16)) {
        LAUNCH(16, 16, 4 * 8 * 16 * 3 + 4 * 4 * 16);   // 1792
    } else {
        LAUNCH(8, 16, 4 * 8 * 8 * 3 + 4 * 4 * 8);      // 896
    }
#undef LAUNCH
}